// Round 3
// baseline (364.055 us; speedup 1.0000x reference)
//
#include <hip/hip_runtime.h>
#include <math.h>

#define NB 16
#define NS 4096
#define NH 768
#define NG 16
#define WRAD 15
#define WLEN 31
#define NH4 192     // NH / 4 float4 columns
#define OUTW (1 + NG)
#define NCH 32      // s-chunks per batch
#define CHUNK 128   // NS / NCH

__device__ inline float4 f4max(float4 a, float4 b) {
    return make_float4(fmaxf(a.x, b.x), fmaxf(a.y, b.y), fmaxf(a.z, b.z), fmaxf(a.w, b.w));
}
__device__ inline float4 f4add(float4 a, float4 b) {
    return make_float4(a.x + b.x, a.y + b.y, a.z + b.z, a.w + b.w);
}
__device__ inline float f4dot(float4 a, float4 b) {
    return a.x * b.x + a.y * b.y + a.z * b.z + a.w * b.w;
}

// Block reduce (blockDim.x == 192): pad LDS to 256, power-of-2 tree.
__device__ inline float block_reduce_192(float v, float* sbuf) {
    int tid = threadIdx.x;
    sbuf[tid] = v;
    if (tid < 64) sbuf[192 + tid] = 0.0f;
    __syncthreads();
    for (int off = 128; off > 0; off >>= 1) {
        if (tid < off) sbuf[tid] += sbuf[tid + off];
        __syncthreads();
    }
    float r = sbuf[0];
    __syncthreads();
    return r;
}

// ---------------------------------------------------------------------------
// One fused kernel.
//   blocks [0, NB*NG)             : gap scores (scheduled first)
//   blocks [NB*NG, NB*NG+NB*NCH)  : text partials; the LAST-arriving block of
//                                   each batch also computes that batch's cls
//                                   score (per-batch completion via device-
//                                   scope fenced atomics -> no 2nd launch, no
//                                   grid-wide barrier tail).
// block = 192 threads; thread t owns float4 column t of H.
// ---------------------------------------------------------------------------
__global__ __launch_bounds__(192) void fused_kernel(
    const float* __restrict__ seq, const float* __restrict__ pooled,
    const int* __restrict__ tt, const int* __restrict__ wm,
    const int* __restrict__ gids,
    const float* __restrict__ gapW, const float* __restrict__ gapb,
    const float* __restrict__ clsW, const float* __restrict__ clsb,
    float* __restrict__ pmax, float* __restrict__ psum,
    unsigned int* __restrict__ arrive, unsigned int* __restrict__ tokcnt,
    float* __restrict__ out) {
    const int blk = blockIdx.x;
    const int tid = threadIdx.x;

    __shared__ float sbuf[256];
    __shared__ int s_idx[CHUNK];
    __shared__ unsigned long long s_wmask[2];
    __shared__ int s_n;
    __shared__ int s_gid;
    __shared__ int s_last;
    __shared__ unsigned int s_tok;

    const float4 ninf4 = make_float4(-INFINITY, -INFINITY, -INFINITY, -INFINITY);
    const float4 zero4 = make_float4(0.f, 0.f, 0.f, 0.f);

    if (blk < NB * NG) {
        // ---------------- gap score ----------------
        const int b = blk >> 4;
        const int g = blk & 15;

        if (tid == 0) s_gid = gids[b * NG + g];
        __syncthreads();
        const int gi = s_gid;

        if (tid < 64) {  // wave 0 computes the 31 validity bits
            bool v = false;
            if (tid < WLEN) {
                const int idx = gi - WRAD + tid;
                v = (idx >= 0) && (idx < NS) && (tt[b * NS + idx] == 0) &&
                    (wm[b * NS + idx] != 0);
            }
            unsigned long long m = __ballot(v);
            if (tid == 0) s_wmask[0] = m;
        }
        __syncthreads();
        const unsigned long long vm = s_wmask[0];
        const float count = (float)__popcll(vm);

        const float4* rowbase = (const float4*)(seq + (size_t)b * NS * NH);
        const float4 gv = rowbase[(size_t)gi * NH4 + tid];

        float4 mx = ninf4;
        float4 sm = zero4;
#pragma unroll 4
        for (int j = 0; j < WLEN; ++j) {
            int idx = gi - WRAD + j;
            idx = idx < 0 ? 0 : (idx > NS - 1 ? NS - 1 : idx);
            const float4 v = rowbase[(size_t)idx * NH4 + tid];  // unconditional
            const bool val = (vm >> j) & 1ull;
            mx.x = val ? fmaxf(mx.x, v.x) : mx.x;
            mx.y = val ? fmaxf(mx.y, v.y) : mx.y;
            mx.z = val ? fmaxf(mx.z, v.z) : mx.z;
            mx.w = val ? fmaxf(mx.w, v.w) : mx.w;
            sm.x += val ? v.x : 0.f;
            sm.y += val ? v.y : 0.f;
            sm.z += val ? v.z : 0.f;
            sm.w += val ? v.w : 0.f;
        }
        const float4 wmax = f4max(mx, zero4);
        // plain division: count==0 -> 0/0 = NaN, matching the reference.
        const float4 wavg = make_float4(sm.x / count, sm.y / count,
                                        sm.z / count, sm.w / count);

        const float4* w0 = (const float4*)gapW;
        const float4* w1 = (const float4*)(gapW + NH);
        const float4* w2 = (const float4*)(gapW + 2 * NH);
        float part = f4dot(gv, w0[tid]) + f4dot(wmax, w1[tid]) + f4dot(wavg, w2[tid]);
        float total = block_reduce_192(part, sbuf);
        if (tid == 0) out[b * OUTW + 1 + g] = total + gapb[0];
    } else {
        // ---------------- text partial ----------------
        const int t = blk - NB * NG;
        const int b = t / NCH;
        const int ss = t % NCH;
        const int s0 = ss * CHUNK;

        // evaluate mask (waves 0,1 fully active), ballot per wave
        if (tid < CHUNK) {
            const int s = s0 + tid;
            bool v = (tt[b * NS + s] == 0) && (wm[b * NS + s] != 0);
            unsigned long long m = __ballot(v);
            if ((tid & 63) == 0) s_wmask[tid >> 6] = m;
        }
        __syncthreads();
        // compact valid row indices into s_idx
        if (tid < CHUNK) {
            const int w = tid >> 6, l = tid & 63;
            const unsigned long long m = s_wmask[w];
            if ((m >> l) & 1ull) {
                int pos = (w ? __popcll(s_wmask[0]) : 0) +
                          __popcll(m & ((1ull << l) - 1ull));
                s_idx[pos] = s0 + tid;
            }
        }
        if (tid == 0)
            s_n = __popcll(s_wmask[0]) + __popcll(s_wmask[1]);
        __syncthreads();
        const int n = s_n;

        const float4* rowbase = (const float4*)(seq + (size_t)b * NS * NH);
        float4 mx = ninf4;
        float4 sm = zero4;
        int i = 0;
        for (; i + 8 <= n; i += 8) {  // unconditional, 8 loads in flight
            float4 v0 = rowbase[(size_t)s_idx[i] * NH4 + tid];
            float4 v1 = rowbase[(size_t)s_idx[i + 1] * NH4 + tid];
            float4 v2 = rowbase[(size_t)s_idx[i + 2] * NH4 + tid];
            float4 v3 = rowbase[(size_t)s_idx[i + 3] * NH4 + tid];
            float4 v4 = rowbase[(size_t)s_idx[i + 4] * NH4 + tid];
            float4 v5 = rowbase[(size_t)s_idx[i + 5] * NH4 + tid];
            float4 v6 = rowbase[(size_t)s_idx[i + 6] * NH4 + tid];
            float4 v7 = rowbase[(size_t)s_idx[i + 7] * NH4 + tid];
            mx = f4max(mx, f4max(f4max(f4max(v0, v1), f4max(v2, v3)),
                                 f4max(f4max(v4, v5), f4max(v6, v7))));
            sm = f4add(sm, f4add(f4add(f4add(v0, v1), f4add(v2, v3)),
                                 f4add(f4add(v4, v5), f4add(v6, v7))));
        }
        for (; i + 4 <= n; i += 4) {
            float4 v0 = rowbase[(size_t)s_idx[i] * NH4 + tid];
            float4 v1 = rowbase[(size_t)s_idx[i + 1] * NH4 + tid];
            float4 v2 = rowbase[(size_t)s_idx[i + 2] * NH4 + tid];
            float4 v3 = rowbase[(size_t)s_idx[i + 3] * NH4 + tid];
            mx = f4max(mx, f4max(f4max(v0, v1), f4max(v2, v3)));
            sm = f4add(sm, f4add(f4add(v0, v1), f4add(v2, v3)));
        }
        for (; i < n; ++i) {
            float4 v = rowbase[(size_t)s_idx[i] * NH4 + tid];
            mx = f4max(mx, v);
            sm = f4add(sm, v);
        }
        const size_t o = ((size_t)(b * NCH + ss)) * NH4 + tid;
        ((float4*)pmax)[o] = mx;
        ((float4*)psum)[o] = sm;

        // publish: release partials, count arrival; last block does cls for b.
        __threadfence();   // all threads: device-scope release of partials
        __syncthreads();
        if (tid == 0) {
            atomicAdd(&tokcnt[b], (unsigned int)n);
            __threadfence();
            unsigned int old = atomicAdd(&arrive[b], 1u);
            s_last = (old == NCH - 1);
            if (s_last) s_tok = atomicAdd(&tokcnt[b], 0u);  // atomic read
        }
        __syncthreads();
        if (s_last) {
            __threadfence();  // all threads: acquire before reading partials
            const float count = (float)s_tok;
            const float4* pm4 = (const float4*)pmax;
            const float4* ps4 = (const float4*)psum;
            float4 cmx = ninf4;
            float4 csm = zero4;
#pragma unroll 8
            for (int ch = 0; ch < NCH; ++ch) {
                const size_t co = ((size_t)(b * NCH + ch)) * NH4 + tid;
                cmx = f4max(cmx, pm4[co]);
                csm = f4add(csm, ps4[co]);
            }
            const float4 tmax = f4max(cmx, zero4);
            const float4 tavg = make_float4(csm.x / count, csm.y / count,
                                            csm.z / count, csm.w / count);
            const float4* p4 = (const float4*)(pooled + (size_t)b * NH);
            const float4* w0 = (const float4*)clsW;
            const float4* w1 = (const float4*)(clsW + NH);
            const float4* w2 = (const float4*)(clsW + 2 * NH);
            float part = f4dot(p4[tid], w0[tid]) + f4dot(tmax, w1[tid]) +
                         f4dot(tavg, w2[tid]);
            float total = block_reduce_192(part, sbuf);
            if (tid == 0) out[b * OUTW + 0] = total + clsb[0];
        }
    }
}

extern "C" void kernel_launch(void* const* d_in, const int* in_sizes, int n_in,
                              void* d_out, int out_size, void* d_ws, size_t ws_size,
                              hipStream_t stream) {
    const float* seq    = (const float*)d_in[0];  // [B,S,H] fp32
    const float* pooled = (const float*)d_in[1];  // [B,H]
    const int*   tt     = (const int*)d_in[2];    // [B,S]
    const int*   wm     = (const int*)d_in[3];    // [B,S]
    const int*   gids   = (const int*)d_in[4];    // [B,G]
    const float* gapW   = (const float*)d_in[5];  // [3H]
    const float* gapb   = (const float*)d_in[6];  // scalar
    const float* clsW   = (const float*)d_in[7];  // [3H]
    const float* clsb   = (const float*)d_in[8];  // scalar
    float* out = (float*)d_out;

    // ws layout: pmax | psum | arrive[NB] | tokcnt[NB]
    float* pmax = (float*)d_ws;
    float* psum = pmax + (size_t)NB * NCH * NH;
    unsigned int* arrive = (unsigned int*)(psum + (size_t)NB * NCH * NH);
    unsigned int* tokcnt = arrive + NB;

    // zero the 2*NB counters (ws is poisoned 0xAA before every timed launch)
    hipMemsetAsync(arrive, 0, 2 * NB * sizeof(unsigned int), stream);

    fused_kernel<<<NB * NG + NB * NCH, 192, 0, stream>>>(
        seq, pooled, tt, wm, gids, gapW, gapb, clsW, clsb,
        pmax, psum, arrive, tokcnt, out);
}

// Round 5
// 318.145 us; speedup vs baseline: 1.1443x; 1.1443x over previous
//
#include <hip/hip_runtime.h>
#include <math.h>

#define NB 16
#define NS 4096
#define NH 768
#define NG 16
#define WRAD 15
#define WLEN 31
#define NH4 192     // NH / 4 float4 columns
#define OUTW (1 + NG)
#define NCH 64      // s-chunks per batch
#define CHUNK 64    // NS / NCH  (one ballot mask per chunk)

__device__ inline float4 f4max(float4 a, float4 b) {
    return make_float4(fmaxf(a.x, b.x), fmaxf(a.y, b.y), fmaxf(a.z, b.z), fmaxf(a.w, b.w));
}
__device__ inline float4 f4add(float4 a, float4 b) {
    return make_float4(a.x + b.x, a.y + b.y, a.z + b.z, a.w + b.w);
}
__device__ inline float f4dot(float4 a, float4 b) {
    return a.x * b.x + a.y * b.y + a.z * b.z + a.w * b.w;
}

// Block reduce (blockDim.x == 192): pad LDS to 256, power-of-2 tree.
__device__ inline float block_reduce_192(float v, float* sbuf) {
    int tid = threadIdx.x;
    sbuf[tid] = v;
    if (tid < 64) sbuf[192 + tid] = 0.0f;
    __syncthreads();
    for (int off = 128; off > 0; off >>= 1) {
        if (tid < off) sbuf[tid] += sbuf[tid + off];
        __syncthreads();
    }
    float r = sbuf[0];
    __syncthreads();
    return r;
}

// ---------------------------------------------------------------------------
// Kernel A (fused): blocks [0, NB*NG) gap scores; blocks [NB*NG, +NB*NCH)
// text partials. Text path is fully STREAMING: unconditional consecutive
// float4 loads (max MLP, no LDS indirection), branch-free select masking.
// 50%-dense random mask => compaction saves 2x bytes but costs ~4x achieved
// BW (R2/R3 evidence: gather ran at ~1.5 TB/s vs 6.6 TB/s streaming fills).
// No cross-block fences/atomics: device-scope fences = per-XCD L2 wb/inv,
// measured +77 us in R3.
// block = 192 threads; thread t owns float4 column t of H.
// NOTE (R4 bug): cast seq to float4* BEFORE row offset — offsets are in
// float4 units (NH4 per row), not float units.
// ---------------------------------------------------------------------------
__global__ __launch_bounds__(192) void fused_kernel(
    const float* __restrict__ seq, const int* __restrict__ tt,
    const int* __restrict__ wm, const int* __restrict__ gids,
    const float* __restrict__ gapW, const float* __restrict__ gapb,
    float* __restrict__ pmax, float* __restrict__ psum,
    int* __restrict__ pcnt, float* __restrict__ out) {
    const int blk = blockIdx.x;
    const int tid = threadIdx.x;

    __shared__ float sbuf[256];
    __shared__ unsigned long long s_mask;
    __shared__ int s_gid;

    const float4 ninf4 = make_float4(-INFINITY, -INFINITY, -INFINITY, -INFINITY);
    const float4 zero4 = make_float4(0.f, 0.f, 0.f, 0.f);

    if (blk < NB * NG) {
        // ---------------- gap score ----------------
        const int b = blk >> 4;
        const int g = blk & 15;

        if (tid == 0) s_gid = gids[b * NG + g];
        __syncthreads();
        const int gi = s_gid;

        if (tid < 64) {  // wave 0 computes the 31 validity bits
            bool v = false;
            if (tid < WLEN) {
                const int idx = gi - WRAD + tid;
                v = (idx >= 0) && (idx < NS) && (tt[b * NS + idx] == 0) &&
                    (wm[b * NS + idx] != 0);
            }
            unsigned long long m = __ballot(v);
            if (tid == 0) s_mask = m;
        }
        __syncthreads();
        const unsigned long long vm = s_mask;
        const float count = (float)__popcll(vm);

        const float4* rowbase = ((const float4*)seq) + (size_t)b * NS * NH4;
        const float4 gv = rowbase[(size_t)gi * NH4 + tid];

        float4 mx = ninf4;
        float4 sm = zero4;
#pragma unroll 4
        for (int j = 0; j < WLEN; ++j) {
            int idx = gi - WRAD + j;
            idx = idx < 0 ? 0 : (idx > NS - 1 ? NS - 1 : idx);
            const float4 v = rowbase[(size_t)idx * NH4 + tid];  // unconditional
            const bool val = (vm >> j) & 1ull;
            mx.x = val ? fmaxf(mx.x, v.x) : mx.x;
            mx.y = val ? fmaxf(mx.y, v.y) : mx.y;
            mx.z = val ? fmaxf(mx.z, v.z) : mx.z;
            mx.w = val ? fmaxf(mx.w, v.w) : mx.w;
            sm.x += val ? v.x : 0.f;
            sm.y += val ? v.y : 0.f;
            sm.z += val ? v.z : 0.f;
            sm.w += val ? v.w : 0.f;
        }
        const float4 wmax = f4max(mx, zero4);
        // plain division: count==0 -> 0/0 = NaN, matching the reference.
        const float4 wavg = make_float4(sm.x / count, sm.y / count,
                                        sm.z / count, sm.w / count);

        const float4* w0 = (const float4*)gapW;
        const float4* w1 = (const float4*)(gapW + NH);
        const float4* w2 = (const float4*)(gapW + 2 * NH);
        float part = f4dot(gv, w0[tid]) + f4dot(wmax, w1[tid]) + f4dot(wavg, w2[tid]);
        float total = block_reduce_192(part, sbuf);
        if (tid == 0) out[b * OUTW + 1 + g] = total + gapb[0];
    } else {
        // ---------------- text partial (streaming) ----------------
        const int t = blk - NB * NG;
        const int b = t / NCH;
        const int ss = t % NCH;
        const int s0 = ss * CHUNK;

        if (tid < 64) {  // wave 0: 64 mask bits for this chunk
            const int s = s0 + tid;
            bool v = (tt[b * NS + s] == 0) && (wm[b * NS + s] != 0);
            unsigned long long m = __ballot(v);
            if (tid == 0) s_mask = m;
        }
        __syncthreads();
        const unsigned long long m = s_mask;

        // float4 pointer arithmetic throughout (R4 bug was float*-scaled NH4)
        const float4* rowbase = ((const float4*)seq) + (size_t)(b * NS + s0) * NH4;
        float4 mx = ninf4;
        float4 sm = zero4;
#pragma unroll 1   // keep 8-deep batches, don't blow VGPRs
        for (int jo = 0; jo < CHUNK; jo += 8) {
            float4 v0 = rowbase[(size_t)(jo + 0) * NH4 + tid];
            float4 v1 = rowbase[(size_t)(jo + 1) * NH4 + tid];
            float4 v2 = rowbase[(size_t)(jo + 2) * NH4 + tid];
            float4 v3 = rowbase[(size_t)(jo + 3) * NH4 + tid];
            float4 v4 = rowbase[(size_t)(jo + 4) * NH4 + tid];
            float4 v5 = rowbase[(size_t)(jo + 5) * NH4 + tid];
            float4 v6 = rowbase[(size_t)(jo + 6) * NH4 + tid];
            float4 v7 = rowbase[(size_t)(jo + 7) * NH4 + tid];
            const float4 vv[8] = {v0, v1, v2, v3, v4, v5, v6, v7};
#pragma unroll
            for (int k = 0; k < 8; ++k) {
                const bool val = (m >> (jo + k)) & 1ull;
                const float4 v = vv[k];
                mx.x = val ? fmaxf(mx.x, v.x) : mx.x;
                mx.y = val ? fmaxf(mx.y, v.y) : mx.y;
                mx.z = val ? fmaxf(mx.z, v.z) : mx.z;
                mx.w = val ? fmaxf(mx.w, v.w) : mx.w;
                sm.x += val ? v.x : 0.f;
                sm.y += val ? v.y : 0.f;
                sm.z += val ? v.z : 0.f;
                sm.w += val ? v.w : 0.f;
            }
        }
        const size_t o = ((size_t)(b * NCH + ss)) * NH4 + tid;
        ((float4*)pmax)[o] = mx;
        ((float4*)psum)[o] = sm;
        if (tid == 0) pcnt[b * NCH + ss] = __popcll(m);
    }
}

// ---------------------------------------------------------------------------
// Kernel B: per-batch cls. Combines NCH partials + counts, fused dot.
// ---------------------------------------------------------------------------
__global__ __launch_bounds__(192) void cls_kernel(
    const float* __restrict__ pooled, const float* __restrict__ pmax,
    const float* __restrict__ psum, const int* __restrict__ pcnt,
    const float* __restrict__ clsW, const float* __restrict__ clsb,
    float* __restrict__ out) {
    const int b = blockIdx.x;
    const int tid = threadIdx.x;
    __shared__ float sbuf[256];

    float c = (tid < NCH) ? (float)pcnt[b * NCH + tid] : 0.f;
    const float count = block_reduce_192(c, sbuf);

    const float4* pm4 = (const float4*)pmax;
    const float4* ps4 = (const float4*)psum;
    float4 mx = make_float4(-INFINITY, -INFINITY, -INFINITY, -INFINITY);
    float4 sm = make_float4(0.f, 0.f, 0.f, 0.f);
#pragma unroll 8
    for (int ch = 0; ch < NCH; ++ch) {
        const size_t o = ((size_t)(b * NCH + ch)) * NH4 + tid;
        mx = f4max(mx, pm4[o]);
        sm = f4add(sm, ps4[o]);
    }
    const float4 zero4 = make_float4(0.f, 0.f, 0.f, 0.f);
    const float4 tmax = f4max(mx, zero4);
    const float4 tavg = make_float4(sm.x / count, sm.y / count,
                                    sm.z / count, sm.w / count);

    const float4* p4 = (const float4*)(pooled + (size_t)b * NH);
    const float4* w0 = (const float4*)clsW;
    const float4* w1 = (const float4*)(clsW + NH);
    const float4* w2 = (const float4*)(clsW + 2 * NH);
    float part = f4dot(p4[tid], w0[tid]) + f4dot(tmax, w1[tid]) + f4dot(tavg, w2[tid]);
    float total = block_reduce_192(part, sbuf);
    if (tid == 0) out[b * OUTW + 0] = total + clsb[0];
}

extern "C" void kernel_launch(void* const* d_in, const int* in_sizes, int n_in,
                              void* d_out, int out_size, void* d_ws, size_t ws_size,
                              hipStream_t stream) {
    const float* seq    = (const float*)d_in[0];  // [B,S,H] fp32
    const float* pooled = (const float*)d_in[1];  // [B,H]
    const int*   tt     = (const int*)d_in[2];    // [B,S]
    const int*   wm     = (const int*)d_in[3];    // [B,S]
    const int*   gids   = (const int*)d_in[4];    // [B,G]
    const float* gapW   = (const float*)d_in[5];  // [3H]
    const float* gapb   = (const float*)d_in[6];  // scalar
    const float* clsW   = (const float*)d_in[7];  // [3H]
    const float* clsb   = (const float*)d_in[8];  // scalar
    float* out = (float*)d_out;

    // ws layout: pmax | psum | pcnt (all written by kernel A before B reads)
    float* pmax = (float*)d_ws;
    float* psum = pmax + (size_t)NB * NCH * NH;
    int*   pcnt = (int*)(psum + (size_t)NB * NCH * NH);

    fused_kernel<<<NB * NG + NB * NCH, 192, 0, stream>>>(
        seq, tt, wm, gids, gapW, gapb, pmax, psum, pcnt, out);
    cls_kernel<<<NB, 192, 0, stream>>>(pooled, pmax, psum, pcnt, clsW, clsb, out);
}